// Round 1
// baseline (122.866 us; speedup 1.0000x reference)
//
#include <hip/hip_runtime.h>

// Problem constants (from reference): x [32,112,112,128] fp32, W [7,7,2,1], b [1]
static constexpr int Bn = 32;
static constexpr int Hn = 112;
static constexpr int Wn = 112;
static constexpr int Cn = 128;                 // channels
static constexpr int NPIX = Bn * Hn * Wn;      // 401408 pixels
static constexpr int N4   = NPIX * (Cn / 4);   // 12,845,056 float4 elements

// ---------------------------------------------------------------------------
// Kernel 1: per-pixel channel mean + max.
// 32 lanes per pixel, each lane loads one float4 (16B) -> full wave reads
// 1024 contiguous bytes covering 2 consecutive pixels. Butterfly reduce
// within the 32-lane group (xor offsets <= 16 stay inside the group).
// ---------------------------------------------------------------------------
__global__ __launch_bounds__(256) void stats_kernel(const float* __restrict__ x,
                                                    float2* __restrict__ stats) {
    const int tid  = blockIdx.x * blockDim.x + threadIdx.x;
    const int pix  = tid >> 5;      // 32 threads per pixel
    const int lane = tid & 31;
    const float4* __restrict__ x4 = reinterpret_cast<const float4*>(x);

    float4 v = x4[(size_t)pix * 32 + lane];
    float s = v.x + v.y + v.z + v.w;
    float m = fmaxf(fmaxf(v.x, v.y), fmaxf(v.z, v.w));

#pragma unroll
    for (int off = 16; off >= 1; off >>= 1) {
        s += __shfl_xor(s, off);
        m = fmaxf(m, __shfl_xor(m, off));
    }
    if (lane == 0) {
        stats[pix] = make_float2(s * (1.0f / 128.0f), m);
    }
}

// ---------------------------------------------------------------------------
// Kernel 2: 7x7 conv (in=2: mean,max; out=1) over the stats plane, SAME
// zero padding, + bias, sigmoid. Thread per pixel; stats plane is 3.2 MB
// so neighbor reads are L2-resident. W (98 floats) staged in LDS.
// ---------------------------------------------------------------------------
__global__ __launch_bounds__(256) void gate_kernel(const float2* __restrict__ stats,
                                                   const float* __restrict__ Wc,
                                                   const float* __restrict__ bias,
                                                   float* __restrict__ gate) {
    __shared__ float w[98];
    if (threadIdx.x < 98) w[threadIdx.x] = Wc[threadIdx.x];
    __syncthreads();

    const int idx = blockIdx.x * blockDim.x + threadIdx.x;
    if (idx >= NPIX) return;

    const int wq = idx % Wn;
    const int t  = idx / Wn;
    const int hq = t % Hn;
    const int bq = t / Hn;

    float acc = bias[0];
    const float2* __restrict__ sb = stats + (size_t)bq * Hn * Wn;

#pragma unroll
    for (int kh = 0; kh < 7; ++kh) {
        const int hh = hq + kh - 3;
        if (hh < 0 || hh >= Hn) continue;
#pragma unroll
        for (int kw = 0; kw < 7; ++kw) {
            const int ww = wq + kw - 3;
            if (ww < 0 || ww >= Wn) continue;
            const float2 sv = sb[hh * Wn + ww];
            acc = fmaf(sv.x, w[(kh * 7 + kw) * 2 + 0], acc);
            acc = fmaf(sv.y, w[(kh * 7 + kw) * 2 + 1], acc);
        }
    }
    gate[idx] = 1.0f / (1.0f + expf(-acc));
}

// ---------------------------------------------------------------------------
// Kernel 3: out = x * gate (gate broadcast across the 128 channels).
// Thread per float4; 32 consecutive lanes share one gate scalar (same-address
// load -> broadcast, L1/L2 resident).
// ---------------------------------------------------------------------------
__global__ __launch_bounds__(256) void mul_kernel(const float* __restrict__ x,
                                                  const float* __restrict__ gate,
                                                  float* __restrict__ out) {
    const size_t i = (size_t)blockIdx.x * blockDim.x + threadIdx.x;
    const float4* __restrict__ x4 = reinterpret_cast<const float4*>(x);
    float4* __restrict__ o4 = reinterpret_cast<float4*>(out);

    const float g = gate[i >> 5];
    float4 v = x4[i];
    v.x *= g; v.y *= g; v.z *= g; v.w *= g;
    o4[i] = v;
}

extern "C" void kernel_launch(void* const* d_in, const int* in_sizes, int n_in,
                              void* d_out, int out_size, void* d_ws, size_t ws_size,
                              hipStream_t stream) {
    const float* x  = (const float*)d_in[0];
    const float* Wc = (const float*)d_in[1];   // [7,7,2,1] HWIO, flat 98
    const float* bb = (const float*)d_in[2];   // [1]
    float* out = (float*)d_out;

    // workspace layout: stats (float2 per pixel) then gate (float per pixel)
    float2* stats = (float2*)d_ws;
    float*  gate  = (float*)((char*)d_ws + (size_t)NPIX * sizeof(float2));
    // needs NPIX*12 = ~4.8 MB of ws

    // K1: 32 threads/pixel -> NPIX*32 threads
    {
        const int threads = 256;
        const int blocks = (NPIX * 32) / threads;   // 50176, exact
        stats_kernel<<<blocks, threads, 0, stream>>>(x, stats);
    }
    // K2: thread per pixel
    {
        const int threads = 256;
        const int blocks = (NPIX + threads - 1) / threads;  // 1568
        gate_kernel<<<blocks, threads, 0, stream>>>(stats, Wc, bb, gate);
    }
    // K3: thread per float4
    {
        const int threads = 256;
        const int blocks = N4 / threads;            // 50176, exact
        mul_kernel<<<blocks, threads, 0, stream>>>(x, gate, out);
    }
}

// Round 3
// 109.343 us; speedup vs baseline: 1.1237x; 1.1237x over previous
//
#include <hip/hip_runtime.h>

// Problem constants (from reference): x [32,112,112,128] fp32, W [7,7,2,1], b [1]
static constexpr int Bn = 32;
static constexpr int Hn = 112;
static constexpr int Wn = 112;
static constexpr int Cn = 128;                 // channels
static constexpr int NPIX = Bn * Hn * Wn;      // 401408 pixels
static constexpr int N4   = NPIX * (Cn / 4);   // 12,845,056 float4 elements

// native clang vector type (works with __builtin_nontemporal_store)
typedef float floatx4 __attribute__((ext_vector_type(4)));

// ---------------------------------------------------------------------------
// Kernel 1: per-pixel channel mean + max.
// 32 lanes per pixel, each lane loads one float4 (16B) -> full wave reads
// 1024 contiguous bytes covering 2 consecutive pixels. Butterfly reduce
// (sum + max) within the 32-lane group. Normal (caching) loads on purpose:
// this pass populates the 256 MB Infinity Cache with x for K3's second read
// (x = 205.5 MB < 256 MB L3).
// ---------------------------------------------------------------------------
__global__ __launch_bounds__(256) void stats_kernel(const float* __restrict__ x,
                                                    float2* __restrict__ stats) {
    const int tid  = blockIdx.x * blockDim.x + threadIdx.x;
    const int pix  = tid >> 5;      // 32 threads per pixel
    const int lane = tid & 31;
    const floatx4* __restrict__ x4 = reinterpret_cast<const floatx4*>(x);

    floatx4 v = x4[(size_t)pix * 32 + lane];
    float s = v.x + v.y + v.z + v.w;
    float m = fmaxf(fmaxf(v.x, v.y), fmaxf(v.z, v.w));

#pragma unroll
    for (int off = 16; off >= 1; off >>= 1) {
        s += __shfl_xor(s, off);
        m = fmaxf(m, __shfl_xor(m, off));
    }
    if (lane == 0) {
        stats[pix] = make_float2(s * (1.0f / 128.0f), m);
    }
}

// ---------------------------------------------------------------------------
// Kernel 2: 7x7 conv (in=2: mean,max; out=1) over the stats plane, SAME
// zero padding, + bias, sigmoid. Thread per pixel; stats plane is 4.8 MB
// so neighbor reads are L2/L3-resident. W (98 floats) staged in LDS.
// ---------------------------------------------------------------------------
__global__ __launch_bounds__(256) void gate_kernel(const float2* __restrict__ stats,
                                                   const float* __restrict__ Wc,
                                                   const float* __restrict__ bias,
                                                   float* __restrict__ gate) {
    __shared__ float w[98];
    if (threadIdx.x < 98) w[threadIdx.x] = Wc[threadIdx.x];
    __syncthreads();

    const int idx = blockIdx.x * blockDim.x + threadIdx.x;
    if (idx >= NPIX) return;

    const int wq = idx % Wn;
    const int t  = idx / Wn;
    const int hq = t % Hn;
    const int bq = t / Hn;

    float acc = bias[0];
    const float2* __restrict__ sb = stats + (size_t)bq * Hn * Wn;

#pragma unroll
    for (int kh = 0; kh < 7; ++kh) {
        const int hh = hq + kh - 3;
        if (hh < 0 || hh >= Hn) continue;
#pragma unroll
        for (int kw = 0; kw < 7; ++kw) {
            const int ww = wq + kw - 3;
            if (ww < 0 || ww >= Wn) continue;
            const float2 sv = sb[hh * Wn + ww];
            acc = fmaf(sv.x, w[(kh * 7 + kw) * 2 + 0], acc);
            acc = fmaf(sv.y, w[(kh * 7 + kw) * 2 + 1], acc);
        }
    }
    gate[idx] = 1.0f / (1.0f + expf(-acc));
}

// ---------------------------------------------------------------------------
// Kernel 3: out = x * gate (gate broadcast across the 128 channels).
// Thread per float4. x loads are normal (should hit Infinity Cache from K1's
// pass); out stores are NON-TEMPORAL so the 205 MB write stream doesn't
// evict x from L3 while we're still re-reading it.
// ---------------------------------------------------------------------------
__global__ __launch_bounds__(256) void mul_kernel(const float* __restrict__ x,
                                                  const float* __restrict__ gate,
                                                  float* __restrict__ out) {
    const size_t i = (size_t)blockIdx.x * blockDim.x + threadIdx.x;
    const floatx4* __restrict__ x4 = reinterpret_cast<const floatx4*>(x);
    floatx4* __restrict__ o4 = reinterpret_cast<floatx4*>(out);

    const float g = gate[i >> 5];
    floatx4 v = x4[i];
    v *= g;
    __builtin_nontemporal_store(v, &o4[i]);
}

extern "C" void kernel_launch(void* const* d_in, const int* in_sizes, int n_in,
                              void* d_out, int out_size, void* d_ws, size_t ws_size,
                              hipStream_t stream) {
    const float* x  = (const float*)d_in[0];
    const float* Wc = (const float*)d_in[1];   // [7,7,2,1] HWIO, flat 98
    const float* bb = (const float*)d_in[2];   // [1]
    float* out = (float*)d_out;

    // workspace layout: stats (float2 per pixel) then gate (float per pixel)
    float2* stats = (float2*)d_ws;
    float*  gate  = (float*)((char*)d_ws + (size_t)NPIX * sizeof(float2));
    // needs NPIX*12 = ~4.8 MB of ws

    // K1: 32 threads/pixel -> NPIX*32 threads
    {
        const int threads = 256;
        const int blocks = (NPIX * 32) / threads;   // 50176, exact
        stats_kernel<<<blocks, threads, 0, stream>>>(x, stats);
    }
    // K2: thread per pixel
    {
        const int threads = 256;
        const int blocks = (NPIX + threads - 1) / threads;  // 1568
        gate_kernel<<<blocks, threads, 0, stream>>>(stats, Wc, bb, gate);
    }
    // K3: thread per float4
    {
        const int threads = 256;
        const int blocks = N4 / threads;            // 50176, exact
        mul_kernel<<<blocks, threads, 0, stream>>>(x, gate, out);
    }
}